// Round 9
// baseline (208.268 us; speedup 1.0000x reference)
//
#include <hip/hip_runtime.h>
#include <math.h>

// Problem constants (from reference)
#define NH 4
#define HD 64
#define HIDDEN 256
#define BS 32
#define NB 64          // NUM_BLOCKS = MAX_LEN/BS = 2048/32
#define SCALE 0.125f
#define INV_SCALE 8.0f

__device__ __forceinline__ float fast_sigmoid(float x) {
    return 1.0f / (1.0f + __expf(-x));
}
__device__ __forceinline__ float readlane_f(float v, int lane) {
    return __int_as_float(__builtin_amdgcn_readlane(__float_as_int(v), lane));
}

// Kernel 1 (unchanged): block means. K in f64 (selection path f64-exact vs np
// reference), V in f32.
__global__ __launch_bounds__(256) void kcmp_kernel(
    const float* __restrict__ k, const float* __restrict__ v,
    const int* __restrict__ x_offsets,
    double* __restrict__ k_cmp, float* __restrict__ v_cmp2) {
    int bb  = blockIdx.x;          // b*NB + blk
    int b   = bb >> 6;
    int blk = bb & 63;
    int tid = threadIdx.x;         // column: h = tid>>6, d = tid&63
    int s0   = x_offsets[b];
    int len  = x_offsets[b + 1] - s0;
    int nblk = len >> 5;
    int h = tid >> 6, d = tid & 63;
    if (blockIdx.y == 0) {
        double acc = 0.0;
        if (blk < nblk) {
            const float* kp = k + (size_t)(s0 + blk * BS) * HIDDEN + tid;
            #pragma unroll
            for (int i = 0; i < BS; ++i) acc += (double)kp[i * HIDDEN];
            acc *= (1.0 / BS);
        }
        k_cmp[((size_t)(b * NH + h) * 64 + blk) * 64 + d] = acc;
    } else {
        float acc = 0.f;
        if (blk < nblk) {
            const float* vp = v + (size_t)(s0 + blk * BS) * HIDDEN + tid;
            #pragma unroll
            for (int i = 0; i < BS; ++i) acc += vp[i * HIDDEN];
            acc *= (1.0f / BS);
        }
        v_cmp2[((size_t)(b * NH + h) * 32 + (blk >> 1)) * 128 + d * 2 + (blk & 1)] = acc;
    }
}

// Kernel 2 (unchanged): cmp scores + top-k + o_cmp. WG = (64-token tile, head).
__global__ __launch_bounds__(256, 3) void cmp_kernel(
    const float* __restrict__ q,
    const int* __restrict__ batch_ids, const int* __restrict__ pos_ids,
    const double* __restrict__ k_cmp, const float* __restrict__ v_cmp2,
    float* __restrict__ oc_buf, int2* __restrict__ idxbuf, int T) {
    int t0   = blockIdx.x * 64;        // tile within one sequence (lengths %256==0)
    int h    = blockIdx.y;
    int tid  = threadIdx.x;
    int wv   = __builtin_amdgcn_readfirstlane(tid >> 6);
    int lane = tid & 63;
    int b    = batch_ids[t0];          // uniform
    int pos0 = pos_ids[t0];            // positions contiguous in tile

    __shared__ __align__(16) char smem[49920];
    float* qs = (float*)smem;                       // [dd][65] padded, 16640 B
    float* ps = qs + 64 * 65;                       // [tok][66] padded, 16896 B
    float* vs = ps + 64 * 66;                       // 4096 floats, 16384 B
    unsigned long long* trip = (unsigned long long*)qs;  // reused after sync

    // stage q (transposed, padded) and v_cmp
    const float* qg = q + (size_t)t0 * HIDDEN + h * HD;
    #pragma unroll
    for (int i = 0; i < 16; ++i) {
        int idx = tid + 256 * i;                    // 4096 elements
        int tok = idx >> 6, dd = idx & 63;
        qs[dd * 65 + tok] = qg[(size_t)tok * HIDDEN + dd];
    }
    const float* vg = v_cmp2 + (size_t)(b * NH + h) * 4096;
    #pragma unroll
    for (int i = 0; i < 16; ++i) vs[tid + 256 * i] = vg[tid + 256 * i];
    __syncthreads();

    int qblk_max = (pos0 + 63) >> 5;
    int m_need   = qblk_max + 2;       // max block index any token's top-3 can touch
    if (m_need > 63) m_need = 63;

    unsigned long long a0 = 0ull, a1 = 0ull, a2 = 0ull;
    if (16 * wv <= m_need) {           // wave-uniform causal skip
        // per-lane (=token) q row in f64 registers
        double qd[64];
        #pragma unroll
        for (int dd = 0; dd < 64; ++dd) qd[dd] = (double)qs[dd * 65 + lane];
        int myqblk = (pos0 + lane) >> 5;

        const double* kcb = k_cmp + ((size_t)(b * NH + h) * 64 + wv * 16) * 64;
        #pragma unroll
        for (int mi = 0; mi < 16; ++mi) {
            int m = wv * 16 + mi;
            const double* kr = kcb + mi * 64;       // uniform -> s_load
            double accA = 0.0, accB = 0.0;          // 2-way split for ILP
            #pragma unroll
            for (int dd = 0; dd < 32; ++dd) {
                accA += qd[2 * dd]     * kr[2 * dd];
                accB += qd[2 * dd + 1] * kr[2 * dd + 1];
            }
            double r = (accA + accB) * 0.125;
            double p64 = 0.0;
            if (m <= myqblk) p64 = r / (1.0 + exp(-r)) * 8.0;   // silu*INV_SCALE
            double selv = (m == myqblk) ? 1.0 : p64;
            ps[lane * 66 + m] = (float)p64;         // exactly 0 beyond qblk
            long long sb = __double_as_longlong(selv);
            unsigned long long kk = (unsigned long long)sb;
            kk = (sb < 0) ? ~kk : (kk | 0x8000000000000000ull);
            kk = (kk & ~63ull) | (unsigned long long)(63 - m);
            // sorted insert (keys unique; predicated selects)
            if (kk > a0)      { a2 = a1; a1 = a0; a0 = kk; }
            else if (kk > a1) { a2 = a1; a1 = kk; }
            else if (kk > a2) { a2 = kk; }
        }
    }
    __syncthreads();                                // qs reads done -> reuse as trip
    trip[(wv * 64 + lane) * 3 + 0] = a0;
    trip[(wv * 64 + lane) * 3 + 1] = a1;
    trip[(wv * 64 + lane) * 3 + 2] = a2;
    __syncthreads();

    // merge 4 sorted triples (tournament, 3 picks); wave 0 stores idx
    if (wv == 0) {
        unsigned long long kk2[4][3];
        #pragma unroll
        for (int w = 0; w < 4; ++w)
            #pragma unroll
            for (int j = 0; j < 3; ++j)
                kk2[w][j] = trip[(w * 64 + lane) * 3 + j];
        int pp[4] = {0, 0, 0, 0};
        int outi[3];
        #pragma unroll
        for (int s = 0; s < 3; ++s) {
            unsigned long long best = 0ull; int bw = 0;
            #pragma unroll
            for (int w = 0; w < 4; ++w) {
                unsigned long long hd_ = (pp[w] == 0) ? kk2[w][0]
                                       : (pp[w] == 1) ? kk2[w][1] : kk2[w][2];
                if (hd_ > best) { best = hd_; bw = w; }
            }
            outi[s] = 63 - (int)(best & 63ull);
            #pragma unroll
            for (int w = 0; w < 4; ++w) if (w == bw) pp[w]++;
        }
        idxbuf[(size_t)(t0 + lane) * NH + h] = make_int2(outi[0], outi[2]);
    }

    // o_cmp: wave wv -> tokens [16wv,16wv+16), lane = d
    float occ[16];
    #pragma unroll
    for (int tt = 0; tt < 16; ++tt) occ[tt] = 0.f;
    int mmax2 = qblk_max >> 1;                      // pair bound, covers tile
    const float2* vs2 = (const float2*)vs;
    for (int m2 = 0; m2 <= mmax2; ++m2) {
        float2 vv = vs2[m2 * 64 + lane];
        #pragma unroll
        for (int tt = 0; tt < 16; ++tt) {
            int tok = wv * 16 + tt;
            float2 pv = *(const float2*)(ps + tok * 66 + 2 * m2);  // uniform b64
            occ[tt] += pv.x * vv.x + pv.y * vv.y;
        }
    }
    #pragma unroll
    for (int tt = 0; tt < 16; ++tt)
        oc_buf[(size_t)(t0 + wv * 16 + tt) * HIDDEN + h * HD + lane] = occ[tt];
}

// Kernel 3a-1 (R19 NEW): build per-(qblock,head) distinct-block worklist.
// One 64-lane wave per (qb,h): reads 32 idx pairs, drops invalid idx2,
// builds union mask U, emits {m, want_mask} entries at fixed stride 64
// (no atomics), writes count, and zeros the o_slc accumulator (d_out slice).
__global__ __launch_bounds__(64) void build_kernel(
    const int* __restrict__ pos_ids, const int2* __restrict__ idxbuf,
    int* __restrict__ cnt_arr, int2* __restrict__ entries,
    float* __restrict__ os_out, int T) {
    int wg   = blockIdx.x;          // qb*NH + h
    int qb   = wg >> 2;
    int h    = wg & 3;
    int t0   = qb * 32;
    int lane = threadIdx.x;

    int pos0 = pos_ids[t0];
    int qblk = pos0 >> 5;

    // zero o_slc slice: tokens [t0,t0+32), dims [h*64, h*64+64)
    float* ob = os_out + (size_t)t0 * HIDDEN + h * HD + lane;
    #pragma unroll
    for (int tk = 0; tk < 32; ++tk) ob[(size_t)tk * HIDDEN] = 0.f;

    int myi0 = -1, myi2 = -1;
    unsigned long long U = 0ull;
    if (lane < 32) {
        int2 ix = idxbuf[(size_t)(t0 + lane) * NH + h];
        myi0 = ix.x;
        myi2 = (ix.y <= qblk) ? ix.y : -1;
        U = (1ull << myi0);
        if (myi2 >= 0) U |= (1ull << myi2);
    }
    #pragma unroll
    for (int off = 1; off < 64; off <<= 1) U |= __shfl_xor(U, off, 64);

    int slot = 0;
    while (U) {
        int m = (int)__builtin_ctzll(U); U &= U - 1;
        unsigned long long wm = __ballot(lane < 32 && (myi0 == m || myi2 == m));
        if (lane == 0) entries[(size_t)wg * 64 + slot] = make_int2(m, (int)wm);
        slot++;
    }
    if (lane == 0) cnt_arr[wg] = slot;
}

// Kernel 3a-2 (R19 NEW): one 64-thread WG per (qb,h,block) task.
// R18 post-mortem: four memory-plan variants all pinned at 80us; invariant =
// 1376 long-lived waves each serially walking ~5.5 block-iterations at ~2
// waves/SIMD (LDS-capped) -> per-block gather+stage latency (~12.5K cy) never
// hidden. R19 changes the unit of parallelism: ~30K independent short tasks.
// Each task: gather ONE block's K (regs) + V (LDS, 8KB) once (bytes
// unchanged), score wanting tokens 2-at-a-time (q direct from global), PV
// from LDS, f32 global atomicAdd into os (each token gets <=2 addends from
// zero -> commutative -> bit-identical to LDS accumulation). Empty slots
// exit on one scalar load.
__global__ __launch_bounds__(64, 4) void slc2_kernel(
    const float* __restrict__ q, const float* __restrict__ k,
    const float* __restrict__ v,
    const int* __restrict__ x_offsets, const int* __restrict__ batch_ids,
    const int* __restrict__ pos_ids,
    const int* __restrict__ cnt_arr, const int2* __restrict__ entries,
    float* __restrict__ os_out, int T) {
    int i  = blockIdx.x;
    int wgidx = (i & 7) * (gridDim.x >> 3) + (i >> 3);  // XCD chunks (grid %8==0)
    int slot = wgidx & 63;
    int wg   = wgidx >> 6;          // qb*NH + h
    if (slot >= cnt_arr[wg]) return;            // scalar load + exit

    int2 e = entries[(size_t)wg * 64 + slot];
    int m = e.x;
    unsigned int want = (unsigned int)e.y;
    int qb = wg >> 2, h = wg & 3;
    int t0 = qb * 32;
    int lane = threadIdx.x;
    int r = lane & 15, cc = lane >> 4;

    int pos0 = pos_ids[t0];
    int s0   = x_offsets[batch_ids[t0]];

    __shared__ float vs_w[32 * 64];   // V block, [row][d], 8192 B

    // gather K block m: lane (r,cc) holds rows {r, 16+r}, 16-float strip
    const float* kb_p = k + (size_t)(s0 + m * BS) * HIDDEN + h * HD;
    float4 kb0[4], kb1[4];
    #pragma unroll
    for (int j = 0; j < 4; ++j) {
        kb0[j] = *(const float4*)(kb_p + (size_t)r * HIDDEN + (cc + 4 * j) * 4);
        kb1[j] = *(const float4*)(kb_p + (size_t)(16 + r) * HIDDEN + (cc + 4 * j) * 4);
    }
    // stage V block m into LDS: groups of 8 named scalars (rule #20)
    {
        const float* vb_p = v + (size_t)(s0 + m * BS) * HIDDEN + h * HD + lane;
        #pragma unroll
        for (int g = 0; g < 4; ++g) {
            const float* p0_ = vb_p + (size_t)(g * 8) * HIDDEN;
            float x0 = p0_[0 * HIDDEN], x1 = p0_[1 * HIDDEN];
            float x2 = p0_[2 * HIDDEN], x3 = p0_[3 * HIDDEN];
            float x4 = p0_[4 * HIDDEN], x5 = p0_[5 * HIDDEN];
            float x6 = p0_[6 * HIDDEN], x7 = p0_[7 * HIDDEN];
            float* d0 = vs_w + (g * 8) * 64 + lane;
            d0[0 * 64] = x0; d0[1 * 64] = x1; d0[2 * 64] = x2; d0[3 * 64] = x3;
            d0[4 * 64] = x4; d0[5 * 64] = x5; d0[6 * 64] = x6; d0[7 * 64] = x7;
        }
    }
    // pin K block in VGPRs (R15 failure mode: loads sunk into token loop)
    #pragma unroll
    for (int j = 0; j < 4; ++j) {
        asm volatile("" : "+v"(kb0[j].x), "+v"(kb0[j].y),
                          "+v"(kb0[j].z), "+v"(kb0[j].w));
        asm volatile("" : "+v"(kb1[j].x), "+v"(kb1[j].y),
                          "+v"(kb1[j].z), "+v"(kb1[j].w));
    }
    int row0 = m * BS + r;

    // token loop, 2 per iteration; q loaded straight from global (both tokens'
    // 8 float4 issue together, single wait). Single wave: no barriers needed,
    // compiler orders ds_write->ds_read via lgkmcnt.
    while (want) {
        int tk0 = (int)__builtin_ctz(want); want &= want - 1;
        int tk1 = -1;
        if (want) { tk1 = (int)__builtin_ctz(want); want &= want - 1; }

        const float4* qr0 = (const float4*)(q + (size_t)(t0 + tk0) * HIDDEN + h * HD);
        const float4* qr1 = (tk1 >= 0)
            ? (const float4*)(q + (size_t)(t0 + tk1) * HIDDEN + h * HD) : qr0;
        float4 qa[4], qb[4];
        #pragma unroll
        for (int j = 0; j < 4; ++j) { qa[j] = qr0[cc + 4 * j]; qb[j] = qr1[cc + 4 * j]; }

        // scores (same FP order per token as R17/R18: j&1 split, 2 shuffles)
        float pa0, pa1, pb0 = 0.f, pb1 = 0.f;
        {
            int pos_tk = pos0 + tk0;
            float psA0 = 0.f, psB0 = 0.f, psA1 = 0.f, psB1 = 0.f;
            #pragma unroll
            for (int j = 0; j < 4; ++j) {
                if (j & 1) {
                    psB0 += qa[j].x * kb0[j].x + qa[j].y * kb0[j].y
                          + qa[j].z * kb0[j].z + qa[j].w * kb0[j].w;
                    psB1 += qa[j].x * kb1[j].x + qa[j].y * kb1[j].y
                          + qa[j].z * kb1[j].z + qa[j].w * kb1[j].w;
                } else {
                    psA0 += qa[j].x * kb0[j].x + qa[j].y * kb0[j].y
                          + qa[j].z * kb0[j].z + qa[j].w * kb0[j].w;
                    psA1 += qa[j].x * kb1[j].x + qa[j].y * kb1[j].y
                          + qa[j].z * kb1[j].z + qa[j].w * kb1[j].w;
                }
            }
            float psum0 = psA0 + psB0, psum1 = psA1 + psB1;
            psum0 += __shfl_xor(psum0, 16, 64); psum0 += __shfl_xor(psum0, 32, 64);
            psum1 += __shfl_xor(psum1, 16, 64); psum1 += __shfl_xor(psum1, 32, 64);
            float scv0 = psum0 * SCALE, scv1 = psum1 * SCALE;
            pa0 = (row0 <= pos_tk)      ? scv0 * fast_sigmoid(scv0) * 16.f : 0.f;
            pa1 = (row0 + 16 <= pos_tk) ? scv1 * fast_sigmoid(scv1) * 16.f : 0.f;
        }
        if (tk1 >= 0) {
            int pos_tk = pos0 + tk1;
            float psA0 = 0.f, psB0 = 0.f, psA1 = 0.f, psB1 = 0.f;
            #pragma unroll
            for (int j = 0; j < 4; ++j) {
                if (j & 1) {
                    psB0 += qb[j].x * kb0[j].x + qb[j].y * kb0[j].y
                          + qb[j].z * kb0[j].z + qb[j].w * kb0[j].w;
                    psB1 += qb[j].x * kb1[j].x + qb[j].y * kb1[j].y
                          + qb[j].z * kb1[j].z + qb[j].w * kb1[j].w;
                } else {
                    psA0 += qb[j].x * kb0[j].x + qb[j].y * kb0[j].y
                          + qb[j].z * kb0[j].z + qb[j].w * kb0[j].w;
                    psA1 += qb[j].x * kb1[j].x + qb[j].y * kb1[j].y
                          + qb[j].z * kb1[j].z + qb[j].w * kb1[j].w;
                }
            }
            float psum0 = psA0 + psB0, psum1 = psA1 + psB1;
            psum0 += __shfl_xor(psum0, 16, 64); psum0 += __shfl_xor(psum0, 32, 64);
            psum1 += __shfl_xor(psum1, 16, 64); psum1 += __shfl_xor(psum1, 32, 64);
            float scv0 = psum0 * SCALE, scv1 = psum1 * SCALE;
            pb0 = (row0 <= pos_tk)      ? scv0 * fast_sigmoid(scv0) * 16.f : 0.f;
            pb1 = (row0 + 16 <= pos_tk) ? scv1 * fast_sigmoid(scv1) * 16.f : 0.f;
        }

        // fused PV: V reads shared across the 2 tokens; 4 independent chains
        float oA0 = 0.f, oA1 = 0.f, oB0 = 0.f, oB1 = 0.f;
        #pragma unroll
        for (int rr = 0; rr < 16; ++rr) {
            float v0 = vs_w[rr * 64 + lane];
            float v1 = vs_w[(16 + rr) * 64 + lane];
            oA0 += readlane_f(pa0, rr) * v0;  oA1 += readlane_f(pa1, rr) * v1;
            oB0 += readlane_f(pb0, rr) * v0;  oB1 += readlane_f(pb1, rr) * v1;
        }
        atomicAdd(&os_out[(size_t)(t0 + tk0) * HIDDEN + h * HD + lane], oA0 + oA1);
        if (tk1 >= 0)
            atomicAdd(&os_out[(size_t)(t0 + tk1) * HIDDEN + h * HD + lane], oB0 + oB1);
    }
}

// Kernel 3b: gate + dual LayerNorm, streaming. WG = 8 tokens x 32 lanes
// (8 dims each). Reads oc_buf (raw o_cmp) and d_out (raw o_slc), writes final.
__global__ __launch_bounds__(256) void ln_kernel(
    const float* __restrict__ q, const float* __restrict__ u,
    const float* __restrict__ Wg_cmp,
    const float* __restrict__ oc_buf, float* __restrict__ io, int T) {
    int tid = threadIdx.x;
    int grp = tid >> 5;           // token within group of 8
    int sub = tid & 31;           // dim strip
    int t   = blockIdx.x * 8 + grp;
    int D0  = sub * 8;            // 8 dims per lane (all within one head)

    const float4* qp = (const float4*)(q + (size_t)t * HIDDEN + D0);
    float4 qa = qp[0], qb = qp[1];
    const float4* wp = (const float4*)(Wg_cmp + D0);   // [NH][64] flat = [256]
    float4 wa = wp[0], wb = wp[1];
    float gp = qa.x * wa.x + qa.y * wa.y + qa.z * wa.z + qa.w * wa.w
             + qb.x * wb.x + qb.y * wb.y + qb.z * wb.z + qb.w * wb.w;
    gp += __shfl_xor(gp, 1, 64);
    gp += __shfl_xor(gp, 2, 64);
    gp += __shfl_xor(gp, 4, 64);   // sum over the head's 8 lanes
    float g = fast_sigmoid(gp);

    const float4* ocp = (const float4*)(oc_buf + (size_t)t * HIDDEN + D0);
    float4 oa = ocp[0], ob = ocp[1];
    oa.x *= g; oa.y *= g; oa.z *= g; oa.w *= g;
    ob.x *= g; ob.y *= g; ob.z *= g; ob.w *= g;
    float4* iop = (float4*)(io + (size_t)t * HIDDEN + D0);
    float4 sa = iop[0], sb = iop[1];

    float sc_ = oa.x + oa.y + oa.z + oa.w + ob.x + ob.y + ob.z + ob.w;
    float sc2 = oa.x * oa.x + oa.y * oa.y + oa.z * oa.z + oa.w * oa.w
              + ob.x * ob.x + ob.y * ob.y + ob.z * ob.z + ob.w * ob.w;
    float ss_ = sa.x + sa.y + sa.z + sa.w + sb.x + sb.y + sb.z + sb.w;
    float ss2 = sa.x * sa.x + sa.y * sa.y + sa.z * sa.z + sa.w * sa.w
              + sb.x * sb.x + sb.y * sb.y + sb.z * sb.z + sb.w * sb.w;
    #pragma unroll
    for (int off = 1; off < 32; off <<= 1) {
        sc_ += __shfl_xor(sc_, off, 64);
        sc2 += __shfl_xor(sc2, off, 64);
        ss_ += __shfl_xor(ss_, off, 64);
        ss2 += __shfl_xor(ss2, off, 64);
    }
    float muc  = sc_ * (1.0f / HIDDEN);
    float varc = sc2 * (1.0f / HIDDEN) - muc * muc;
    float mus  = ss_ * (1.0f / HIDDEN);
    float vars = ss2 * (1.0f / HIDDEN) - mus * mus;
    float rc = rsqrtf(varc + 1e-6f), rs = rsqrtf(vars + 1e-6f);

    const float4* up = (const float4*)(u + (size_t)t * HIDDEN + D0);
    float4 ua = up[0], ub = up[1];
    float4 o0, o1;
    o0.x = ((oa.x - muc) * rc + (sa.x - mus) * rs) * ua.x;
    o0.y = ((oa.y - muc) * rc + (sa.y - mus) * rs) * ua.y;
    o0.z = ((oa.z - muc) * rc + (sa.z - mus) * rs) * ua.z;
    o0.w = ((oa.w - muc) * rc + (sa.w - mus) * rs) * ua.w;
    o1.x = ((ob.x - muc) * rc + (sb.x - mus) * rs) * ub.x;
    o1.y = ((ob.y - muc) * rc + (sb.y - mus) * rs) * ub.y;
    o1.z = ((ob.z - muc) * rc + (sb.z - mus) * rs) * ub.z;
    o1.w = ((ob.w - muc) * rc + (sb.w - mus) * rs) * ub.w;
    iop[0] = o0; iop[1] = o1;
}

extern "C" void kernel_launch(void* const* d_in, const int* in_sizes, int n_in,
                              void* d_out, int out_size, void* d_ws, size_t ws_size,
                              hipStream_t stream) {
    const float* q      = (const float*)d_in[0];
    const float* k      = (const float*)d_in[1];
    const float* v      = (const float*)d_in[2];
    const float* u      = (const float*)d_in[3];
    const float* Wg_cmp = (const float*)d_in[4];
    // d_in[5] = Wg_slc: dead code in the reference (computed, never used)
    const int* x_offsets = (const int*)d_in[6];
    const int* batch_ids = (const int*)d_in[7];
    const int* pos_ids   = (const int*)d_in[8];

    int T = in_sizes[0] / HIDDEN;   // 11008; all lengths are multiples of 256
    int B = in_sizes[6] - 1;

    double* k_cmp  = (double*)d_ws;                                 // B*NH*4096 doubles
    float*  v_cmp2 = (float*)(k_cmp + (size_t)B * NH * 4096);       // B*NH*4096 floats
    float*  oc_buf = v_cmp2 + (size_t)B * NH * 4096;                // T*256 floats
    int2*   idxbuf = (int2*)(oc_buf + (size_t)T * HIDDEN);          // T*NH int2
    int2*   entries = idxbuf + (size_t)T * NH;                      // (T/32)*NH*64 int2
    int*    cnt_arr = (int*)(entries + (size_t)(T / 32) * NH * 64); // (T/32)*NH int

    int nwg = (T / 32) * NH;        // 1376

    kcmp_kernel<<<dim3(B * NB, 2), 256, 0, stream>>>(k, v, x_offsets, k_cmp, v_cmp2);
    cmp_kernel<<<dim3(T / 64, NH), 256, 0, stream>>>(
        q, batch_ids, pos_ids, k_cmp, v_cmp2, oc_buf, idxbuf, T);
    // 3a-1: worklist + zero o_slc accumulator (d_out)
    build_kernel<<<dim3(nwg), 64, 0, stream>>>(
        pos_ids, idxbuf, cnt_arr, entries, (float*)d_out, T);
    // 3a-2: one WG per (qb,h,block) task; atomic-accumulate o_slc into d_out
    slc2_kernel<<<dim3(nwg * 64), 64, 0, stream>>>(
        q, k, v, x_offsets, batch_ids, pos_ids, cnt_arr, entries,
        (float*)d_out, T);
    // 3b: gate + LN; reads oc_buf + d_out (o_slc), overwrites d_out
    ln_kernel<<<dim3(T / 8), 256, 0, stream>>>(
        q, u, Wg_cmp, oc_buf, (float*)d_out, T);
}